// Round 6
// baseline (209.640 us; speedup 1.0000x reference)
//
#include <hip/hip_runtime.h>
#include <hip/hip_bf16.h>
#include <stdint.h>

#define NB 256
#define LQ 128
#define LC 512
#define DIM 384

typedef __attribute__((ext_vector_type(8))) short short8;
typedef __attribute__((ext_vector_type(4))) float f4;
typedef __attribute__((ext_vector_type(2))) unsigned int u32x2;

__device__ __forceinline__ unsigned int pk2bf(float a, float b) {
  union { float f; uint32_t u; } x, y; x.f = a; y.f = b;
  uint32_t lo = (x.u + 0x7fffu + ((x.u >> 16) & 1u)) >> 16;
  uint32_t hi = (y.u + 0x7fffu + ((y.u >> 16) & 1u)) >> 16;
  return lo | (hi << 16);
}

__device__ __forceinline__ void gload16(const void* g, void* l) {
  __builtin_amdgcn_global_load_lds(
      (const __attribute__((address_space(1))) void*)g,
      (__attribute__((address_space(3))) void*)l, 16, 0, 0);
}

__device__ __forceinline__ void barrier_pinned() {
  __builtin_amdgcn_sched_barrier(0);
  __builtin_amdgcn_s_barrier();
  __builtin_amdgcn_sched_barrier(0);
}

// ============================== K1: normalize + pool =========================
// grid 2048 (8 blocks per batch), 256 threads, no barriers in the row loop.
// Each wave: 4 q rows + 16 c rows. Per row: sumsq -> inv norm, masked pooled
// partials (f32), write normalized bf16 row. Partials -> ws.
__device__ __forceinline__ void proc_row(const float* __restrict__ src, int mk,
                                         unsigned short* __restrict__ dst, int lane,
                                         f4& p0, f4& p1, float& cnt) {
  const f4* p = (const f4*)src;
  const f4 va = p[lane];
  const f4 vb = p[64 + (lane & 31)];
  float ss = va.x*va.x + va.y*va.y + va.z*va.z + va.w*va.w;
  if (lane < 32) ss += vb.x*vb.x + vb.y*vb.y + vb.z*vb.z + vb.w*vb.w;
#pragma unroll
  for (int o = 32; o; o >>= 1) ss += __shfl_xor(ss, o);
  const float inv = 1.0f / fmaxf(sqrtf(ss), 1e-12f);
  const float fm = (float)mk;
  p0 += va * fm;
  if (lane < 32) p1 += vb * fm;
  cnt += fm;
  u32x2 w0; w0[0] = pk2bf(va.x * inv, va.y * inv); w0[1] = pk2bf(va.z * inv, va.w * inv);
  *(u32x2*)(dst + 4 * lane) = w0;
  if (lane < 32) {
    u32x2 w1; w1[0] = pk2bf(vb.x * inv, vb.y * inv); w1[1] = pk2bf(vb.z * inv, vb.w * inv);
    *(u32x2*)(dst + 256 + 4 * lane) = w1;
  }
}

__global__ __launch_bounds__(256, 8)
void normalize_pool(const float* __restrict__ qtok, const float* __restrict__ ctok,
                    const int* __restrict__ qm, const int* __restrict__ cm,
                    unsigned short* __restrict__ qn, unsigned short* __restrict__ cn,
                    float* __restrict__ pp, float* __restrict__ nn) {
  __shared__ float s_red[4][2][DIM];
  __shared__ float s_cnt[4][2];
  const int bid = blockIdx.x;
  const int b = bid >> 3, s = bid & 7;
  const int tid = threadIdx.x, wave = tid >> 6, lane = tid & 63;

  f4 pq0 = {0,0,0,0}, pq1 = {0,0,0,0}, pc0 = {0,0,0,0}, pc1 = {0,0,0,0};
  float cq = 0.f, cc = 0.f;

#pragma unroll
  for (int i = 0; i < 4; ++i) {
    const int row = b * LQ + s * 16 + wave * 4 + i;
    proc_row(qtok + (size_t)row * DIM, qm[row], qn + (size_t)row * DIM, lane, pq0, pq1, cq);
  }
#pragma unroll 4
  for (int i = 0; i < 16; ++i) {
    const int row = b * LC + s * 64 + wave * 16 + i;
    proc_row(ctok + (size_t)row * DIM, cm[row], cn + (size_t)row * DIM, lane, pc0, pc1, cc);
  }

  *(f4*)&s_red[wave][0][4 * lane] = pq0;
  if (lane < 32) *(f4*)&s_red[wave][0][256 + 4 * lane] = pq1;
  *(f4*)&s_red[wave][1][4 * lane] = pc0;
  if (lane < 32) *(f4*)&s_red[wave][1][256 + 4 * lane] = pc1;
  if (lane == 0) { s_cnt[wave][0] = cq; s_cnt[wave][1] = cc; }
  __syncthreads();

  // FIX (round 5 bug): 256 threads must cover DIM=384 -> stride loop.
  for (int d = tid; d < DIM; d += 256) {
    float sq = 0.f, sc = 0.f;
#pragma unroll
    for (int w = 0; w < 4; ++w) { sq += s_red[w][0][d]; sc += s_red[w][1][d]; }
    pp[(size_t)bid * 768 + d] = sq;
    pp[(size_t)bid * 768 + DIM + d] = sc;
  }
  if (tid == 0) {
    nn[bid * 2]     = s_cnt[0][0] + s_cnt[1][0] + s_cnt[2][0] + s_cnt[3][0];
    nn[bid * 2 + 1] = s_cnt[0][1] + s_cnt[1][1] + s_cnt[2][1] + s_cnt[3][1];
  }
}

// ============================== K2: maxsim (MFMA) ============================
// grid 512: (b = bid>>1, c-half s = bid&1). 8 waves. q A-frags in registers;
// c staged via global_load_lds into a 3-buffer ring (32 rows x 768B, swizzled),
// counted vmcnt(3), one barrier per stage. Output: per-half row-max [128].
__global__ __launch_bounds__(512, 4)
void maxsim(const unsigned short* __restrict__ qn, const unsigned short* __restrict__ cn,
            const int* __restrict__ cm, float* __restrict__ ws_rm) {
  __shared__ __attribute__((aligned(128))) char ring[3][24576];
  __shared__ int s_cm[256];
  const int bid = blockIdx.x;
  const int b = bid >> 1, s = bid & 1;
  const int tid = threadIdx.x, wave = tid >> 6, lane = tid & 63;
  const int rA = lane & 15, hi = lane >> 4;

  if (tid < 256) s_cm[tid] = cm[b * LC + s * 256 + tid];
  __syncthreads();

  const char* qbase = (const char*)(qn + (size_t)b * LQ * DIM);
  const char* cbase = (const char*)(cn + (size_t)b * LC * DIM) + (size_t)s * 256 * 768;

  // per-lane swizzled DMA source offsets for one 32x768B tile (3 issues/lane):
  // LDS chunk n=(row,col) holds global chunk (row, col^(row&7)).
  int goff[3];
#pragma unroll
  for (int j = 0; j < 3; ++j) {
    const unsigned n = (unsigned)j * 512u + (unsigned)wave * 64u + (unsigned)lane;
    const unsigned row = n / 48u, col = n % 48u;
    goff[j] = (int)(row * 768u + ((col ^ (row & 7u)) << 4));
  }

  // ---- q prologue round A: tiles 0..2 -> bufs 0..2
#pragma unroll
  for (int tile = 0; tile < 3; ++tile) {
    char* dst = ring[tile] + wave * 1024;
#pragma unroll
    for (int j = 0; j < 3; ++j) gload16(qbase + tile * 24576 + goff[j], dst + j * 8192);
  }
  asm volatile("s_waitcnt vmcnt(0)" ::: "memory");
  barrier_pinned();

  short8 A[12] = {};
  if (wave < 6) {
    const char* bp = ring[wave >> 1];
    const int lr = (wave & 1) * 16 + rA;
#pragma unroll
    for (int kk = 0; kk < 12; ++kk)
      A[kk] = *(const short8*)(bp + lr * 768 + (((kk * 4 + hi) ^ (lr & 7)) << 4));
    asm volatile("s_waitcnt lgkmcnt(0)" ::: "memory");
  }
  barrier_pinned();

  // ---- round B: tile 3 -> buf 0 (waves 6,7 read their frags)
  {
    char* dst = ring[0] + wave * 1024;
#pragma unroll
    for (int j = 0; j < 3; ++j) gload16(qbase + 3 * 24576 + goff[j], dst + j * 8192);
  }
  asm volatile("s_waitcnt vmcnt(0)" ::: "memory");
  barrier_pinned();
  if (wave >= 6) {
    const char* bp = ring[0];
    const int lr = (wave - 6) * 16 + rA;
#pragma unroll
    for (int kk = 0; kk < 12; ++kk)
      A[kk] = *(const short8*)(bp + lr * 768 + (((kk * 4 + hi) ^ (lr & 7)) << 4));
    asm volatile("s_waitcnt lgkmcnt(0)" ::: "memory");
  }
  barrier_pinned();

  // ---- issue c0 -> buf1, c1 -> buf2
#pragma unroll
  for (int t0 = 0; t0 < 2; ++t0) {
    char* dst = ring[t0 + 1] + wave * 1024;
#pragma unroll
    for (int j = 0; j < 3; ++j) gload16(cbase + (size_t)t0 * 24576 + goff[j], dst + j * 8192);
  }

  float rm[4] = {-1e9f, -1e9f, -1e9f, -1e9f};

  // ---- 8 c stages; stage t reads buf[(t+1)%3], issues c(t+2) -> buf[(t+3)%3]
#pragma unroll
  for (int t = 0; t < 8; ++t) {
    if (t == 7) { asm volatile("s_waitcnt vmcnt(0)" ::: "memory"); }
    else        { asm volatile("s_waitcnt vmcnt(3)" ::: "memory"); }
    barrier_pinned();

    const char* bp = ring[(t + 1) % 3];
    f4 acc0 = {0,0,0,0}, acc1 = {0,0,0,0};
#pragma unroll
    for (int kk = 0; kk < 12; ++kk) {
      const int sw = ((kk * 4 + hi) ^ (rA & 7)) << 4;
      const short8 b0 = *(const short8*)(bp + rA * 768 + sw);
      const short8 b1 = *(const short8*)(bp + (rA + 16) * 768 + sw);
      acc0 = __builtin_amdgcn_mfma_f32_16x16x32_bf16(A[kk], b0, acc0, 0, 0, 0);
      acc1 = __builtin_amdgcn_mfma_f32_16x16x32_bf16(A[kk], b1, acc1, 0, 0, 0);
    }
    if (t + 2 < 8) {
      char* dst = ring[(t + 3) % 3] + wave * 1024;
#pragma unroll
      for (int j = 0; j < 3; ++j) gload16(cbase + (size_t)(t + 2) * 24576 + goff[j], dst + j * 8192);
    }
    const bool v0 = s_cm[t * 32 + rA] != 0;
    const bool v1 = s_cm[t * 32 + rA + 16] != 0;
#pragma unroll
    for (int r = 0; r < 4; ++r) {
      const float a0 = v0 ? acc0[r] : -1e9f;
      const float a1 = v1 ? acc1[r] : -1e9f;
      rm[r] = fmaxf(rm[r], fmaxf(a0, a1));
    }
  }

  // ---- reduce row-max across the 16 col-lanes; write per-half row-max
#pragma unroll
  for (int r = 0; r < 4; ++r) {
#pragma unroll
    for (int o = 1; o < 16; o <<= 1) rm[r] = fmaxf(rm[r], __shfl_xor(rm[r], o));
  }
  if (rA == 0) {
#pragma unroll
    for (int r = 0; r < 4; ++r)
      ws_rm[(size_t)bid * LQ + wave * 16 + hi * 4 + r] = rm[r];
  }
}

// ============================== K3: merge + MLP ==============================
__global__ __launch_bounds__(DIM)
void merge_mlp(const float* __restrict__ ws_rm, const float* __restrict__ pp,
               const float* __restrict__ nn, const int* __restrict__ qm,
               const float* __restrict__ W1, const float* __restrict__ b1,
               const float* __restrict__ W2, const float* __restrict__ b2,
               float* __restrict__ late, float* __restrict__ emb) {
  __shared__ float s_q[DIM], s_c[DIM], s_hq[DIM], s_hc[DIM];
  __shared__ float s_red[2][6], s_l[2];
  const int b = blockIdx.x;
  const int d = threadIdx.x;

  if (d < LQ) {
    const float m = fmaxf(ws_rm[(size_t)(2 * b) * LQ + d],
                          ws_rm[(size_t)(2 * b + 1) * LQ + d]);
    float ps = qm[b * LQ + d] ? m : 0.f;
#pragma unroll
    for (int o = 32; o; o >>= 1) ps += __shfl_xor(ps, o);
    if ((d & 63) == 0) s_l[d >> 6] = ps;
  }
  float sq = 0.f, sc = 0.f, nq = 0.f, nc = 0.f;
#pragma unroll
  for (int s = 0; s < 8; ++s) {
    sq += pp[(size_t)(b * 8 + s) * 768 + d];
    sc += pp[(size_t)(b * 8 + s) * 768 + DIM + d];
    nq += nn[(b * 8 + s) * 2];
    nc += nn[(b * 8 + s) * 2 + 1];
  }
  s_q[d] = sq / fmaxf(nq, 1e-9f);
  s_c[d] = sc / fmaxf(nc, 1e-9f);
  __syncthreads();

  float aq = b1[d], ac = b1[d];
#pragma unroll 8
  for (int k = 0; k < DIM; ++k) {
    const float w = W1[k * DIM + d];
    aq = fmaf(s_q[k], w, aq);
    ac = fmaf(s_c[k], w, ac);
  }
  s_hq[d] = fmaxf(aq, 0.f);
  s_hc[d] = fmaxf(ac, 0.f);
  __syncthreads();
  float pq = b2[d], pc = b2[d];
#pragma unroll 8
  for (int k = 0; k < DIM; ++k) {
    const float w = W2[k * DIM + d];
    pq = fmaf(s_hq[k], w, pq);
    pc = fmaf(s_hc[k], w, pc);
  }
  float q2 = pq * pq, c2 = pc * pc;
#pragma unroll
  for (int o = 32; o; o >>= 1) { q2 += __shfl_xor(q2, o); c2 += __shfl_xor(c2, o); }
  if ((d & 63) == 0) { s_red[0][d >> 6] = q2; s_red[1][d >> 6] = c2; }
  __syncthreads();
  float tq = 0.f, tc = 0.f;
#pragma unroll
  for (int w = 0; w < 6; ++w) { tq += s_red[0][w]; tc += s_red[1][w]; }
  emb[(size_t)b * DIM + d] = pq * (1.0f / fmaxf(sqrtf(tq), 1e-12f));
  emb[(size_t)(NB + b) * DIM + d] = pc * (1.0f / fmaxf(sqrtf(tc), 1e-12f));
  if (d == 0) late[b] = s_l[0] + s_l[1];
}

// ============================== K4: contrast =================================
__global__ __launch_bounds__(NB)
void contrast_kernel(const float* __restrict__ emb, float* __restrict__ out0) {
  __shared__ float s_q[DIM];
  const int i = blockIdx.x;
  for (int k = threadIdx.x; k < DIM; k += NB) s_q[k] = emb[(size_t)i * DIM + k];
  __syncthreads();
  const float* ce = emb + (size_t)(NB + threadIdx.x) * DIM;
  float acc = 0.f;
#pragma unroll 8
  for (int k = 0; k < DIM; ++k) acc = fmaf(s_q[k], ce[k], acc);
  out0[(size_t)i * NB + threadIdx.x] = acc / 0.07f;
}

// ===================== Fallback (round-1 proven path) ========================
#define TCD 32
#define QP 392
__device__ __forceinline__ unsigned short f2bf(float x) {
  union { float f; uint32_t u; } c; c.f = x;
  return (unsigned short)((c.u + 0x7fffu + ((c.u >> 16) & 1u)) >> 16);
}

__global__ __launch_bounds__(512, 1)
void fused_v1(const float* __restrict__ qtok, const float* __restrict__ ctok,
              const int* __restrict__ qm, const int* __restrict__ cm,
              float* __restrict__ pooled, float* __restrict__ late) {
  __shared__ unsigned short s_q[LQ][QP];
  __shared__ unsigned short s_c[TCD][QP];
  __shared__ float s_pq[8][DIM];
  __shared__ float s_pc[8][DIM];
  __shared__ float s_cnt[2][8];
  __shared__ int   s_cval[TCD];
  __shared__ float s_wsum[8];

  const int b = blockIdx.x;
  const int tid = threadIdx.x;
  const int wave = tid >> 6;
  const int lane = tid & 63;
  const int rA = lane & 15;
  const int kof = (lane >> 4) * 8;

  const float* qb = qtok + (size_t)b * LQ * DIM;
  const float* cb = ctok + (size_t)b * LC * DIM;
  const int* qmb = qm + b * LQ;
  const int* cmb = cm + b * LC;

  float pq[6] = {0.f,0.f,0.f,0.f,0.f,0.f};
  float cq = 0.f;
  for (int r0 = 0; r0 < 16; ++r0) {
    const int r = wave * 16 + r0;
    const float* src = qb + r * DIM;
    float v[6], ss = 0.f;
#pragma unroll
    for (int j = 0; j < 6; ++j) { v[j] = src[lane + 64 * j]; ss += v[j] * v[j]; }
#pragma unroll
    for (int o = 32; o; o >>= 1) ss += __shfl_xor(ss, o);
    const float inv = 1.0f / fmaxf(sqrtf(ss), 1e-12f);
    const float fm = (float)qmb[r];
#pragma unroll
    for (int j = 0; j < 6; ++j) {
      s_q[r][lane + 64 * j] = f2bf(v[j] * inv);
      pq[j] = fmaf(v[j], fm, pq[j]);
    }
    cq += fm;
  }
#pragma unroll
  for (int j = 0; j < 6; ++j) s_pq[wave][lane + 64 * j] = pq[j];
  if (lane == 0) s_cnt[0][wave] = cq;

  float rm[4] = {-1e9f, -1e9f, -1e9f, -1e9f};
  float pc[6] = {0.f,0.f,0.f,0.f,0.f,0.f};
  float cc = 0.f;

  for (int t = 0; t < LC / TCD; ++t) {
    __syncthreads();
#pragma unroll
    for (int r0 = 0; r0 < 4; ++r0) {
      const int r = wave * 4 + r0;
      const int crow = t * TCD + r;
      const float* src = cb + crow * DIM;
      float v[6], ss = 0.f;
#pragma unroll
      for (int j = 0; j < 6; ++j) { v[j] = src[lane + 64 * j]; ss += v[j] * v[j]; }
#pragma unroll
      for (int o = 32; o; o >>= 1) ss += __shfl_xor(ss, o);
      const float inv = 1.0f / fmaxf(sqrtf(ss), 1e-12f);
      const int mk = cmb[crow];
      const float fm = (float)mk;
#pragma unroll
      for (int j = 0; j < 6; ++j) {
        s_c[r][lane + 64 * j] = f2bf(v[j] * inv);
        pc[j] = fmaf(v[j], fm, pc[j]);
      }
      cc += fm;
      if (lane == 0) s_cval[r] = mk;
    }
    __syncthreads();

    const unsigned short* ap  = &s_q[wave * 16 + rA][kof];
    const unsigned short* bp0 = &s_c[rA][kof];
    const unsigned short* bp1 = &s_c[rA + 16][kof];
    f4 acc0 = {0.f,0.f,0.f,0.f};
    f4 acc1 = {0.f,0.f,0.f,0.f};
#pragma unroll
    for (int kk = 0; kk < 12; ++kk) {
      short8 a  = *(const short8*)(ap  + kk * 32);
      short8 b0 = *(const short8*)(bp0 + kk * 32);
      short8 b1 = *(const short8*)(bp1 + kk * 32);
      acc0 = __builtin_amdgcn_mfma_f32_16x16x32_bf16(a, b0, acc0, 0, 0, 0);
      acc1 = __builtin_amdgcn_mfma_f32_16x16x32_bf16(a, b1, acc1, 0, 0, 0);
    }
    const bool v0 = s_cval[rA] != 0;
    const bool v1 = s_cval[rA + 16] != 0;
#pragma unroll
    for (int r = 0; r < 4; ++r) {
      const float a0 = v0 ? acc0[r] : -1e9f;
      const float a1 = v1 ? acc1[r] : -1e9f;
      rm[r] = fmaxf(rm[r], fmaxf(a0, a1));
    }
  }

#pragma unroll
  for (int j = 0; j < 6; ++j) s_pc[wave][lane + 64 * j] = pc[j];
  if (lane == 0) s_cnt[1][wave] = cc;

#pragma unroll
  for (int r = 0; r < 4; ++r) {
#pragma unroll
    for (int o = 1; o < 16; o <<= 1) rm[r] = fmaxf(rm[r], __shfl_xor(rm[r], o));
  }
  float ps = 0.f;
  if (rA == 0) {
    const int rowb = wave * 16 + (lane >> 4) * 4;
#pragma unroll
    for (int r = 0; r < 4; ++r) ps += qmb[rowb + r] ? rm[r] : 0.f;
  }
#pragma unroll
  for (int o = 32; o; o >>= 1) ps += __shfl_xor(ps, o);
  if (lane == 0) s_wsum[wave] = ps;
  __syncthreads();

  if (tid < DIM) {
    float sq = 0.f, sc = 0.f, nq = 0.f, nc = 0.f;
#pragma unroll
    for (int w = 0; w < 8; ++w) {
      sq += s_pq[w][tid];
      sc += s_pc[w][tid];
      nq += s_cnt[0][w];
      nc += s_cnt[1][w];
    }
    pooled[b * DIM + tid] = sq / fmaxf(nq, 1e-9f);
    pooled[(NB + b) * DIM + tid] = sc / fmaxf(nc, 1e-9f);
  }
  if (tid == 0) {
    float tot = 0.f;
#pragma unroll
    for (int w = 0; w < 8; ++w) tot += s_wsum[w];
    late[b] = tot;
  }
}

__global__ __launch_bounds__(DIM)
void mlp_v1(const float* __restrict__ pooled,
            const float* __restrict__ W1, const float* __restrict__ b1,
            const float* __restrict__ W2, const float* __restrict__ b2,
            float* __restrict__ emb) {
  __shared__ float s_in[DIM];
  __shared__ float s_h[DIM];
  __shared__ float s_red[6];
  const int row = blockIdx.y * NB + blockIdx.x;
  const int d = threadIdx.x;
  s_in[d] = pooled[(size_t)row * DIM + d];
  __syncthreads();
  float acc = b1[d];
#pragma unroll 8
  for (int k = 0; k < DIM; ++k) acc = fmaf(s_in[k], W1[k * DIM + d], acc);
  s_h[d] = fmaxf(acc, 0.f);
  __syncthreads();
  float p = b2[d];
#pragma unroll 8
  for (int k = 0; k < DIM; ++k) p = fmaf(s_h[k], W2[k * DIM + d], p);
  float ss = p * p;
#pragma unroll
  for (int o = 32; o; o >>= 1) ss += __shfl_xor(ss, o);
  if ((d & 63) == 0) s_red[d >> 6] = ss;
  __syncthreads();
  float tot = 0.f;
#pragma unroll
  for (int w = 0; w < 6; ++w) tot += s_red[w];
  emb[(size_t)row * DIM + d] = p * (1.0f / fmaxf(sqrtf(tot), 1e-12f));
}

// ============================== launch =======================================
extern "C" void kernel_launch(void* const* d_in, const int* in_sizes, int n_in,
                              void* d_out, int out_size, void* d_ws, size_t ws_size,
                              hipStream_t stream) {
  const float* qtok = (const float*)d_in[0];
  const float* ctok = (const float*)d_in[1];
  const int*   qmm  = (const int*)d_in[2];
  const int*   cmm  = (const int*)d_in[3];
  const float* W1   = (const float*)d_in[4];
  const float* b1   = (const float*)d_in[5];
  const float* W2   = (const float*)d_in[6];
  const float* b2   = (const float*)d_in[7];

  float* out0 = (float*)d_out;   // [NB*NB]
  float* late = out0 + NB * NB;  // [NB]

  // main-path workspace layout
  const size_t PP_N   = (size_t)2048 * 768;
  const size_t NN_N   = 4096;
  const size_t RM_N   = (size_t)512 * LQ;
  const size_t EMB_N  = (size_t)2 * NB * DIM;
  const size_t QN_N   = (size_t)NB * LQ * DIM;
  const size_t CN_N   = (size_t)NB * LC * DIM;
  const size_t NEED   = (PP_N + NN_N + RM_N + EMB_N) * 4 + (QN_N + CN_N) * 2;

  if (ws_size >= NEED) {
    float* pp  = (float*)d_ws;
    float* nn  = pp + PP_N;
    float* rm  = nn + NN_N;
    float* emb = rm + RM_N;
    unsigned short* qn = (unsigned short*)(emb + EMB_N);
    unsigned short* cn = qn + QN_N;

    hipLaunchKernelGGL(normalize_pool, dim3(2048), dim3(256), 0, stream,
                       qtok, ctok, qmm, cmm, qn, cn, pp, nn);
    hipLaunchKernelGGL(maxsim, dim3(512), dim3(512), 0, stream, qn, cn, cmm, rm);
    hipLaunchKernelGGL(merge_mlp, dim3(NB), dim3(DIM), 0, stream,
                       rm, pp, nn, qmm, W1, b1, W2, b2, late, emb);
    hipLaunchKernelGGL(contrast_kernel, dim3(NB), dim3(NB), 0, stream, emb, out0);
  } else {
    float* pooled = (float*)d_ws;            // [2*NB][DIM]
    float* emb    = pooled + 2 * NB * DIM;   // [2*NB][DIM]
    hipLaunchKernelGGL(fused_v1, dim3(NB), dim3(512), 0, stream,
                       qtok, ctok, qmm, cmm, pooled, late);
    hipLaunchKernelGGL(mlp_v1, dim3(NB, 2), dim3(DIM), 0, stream,
                       pooled, W1, b1, W2, b2, emb);
    hipLaunchKernelGGL(contrast_kernel, dim3(NB), dim3(NB), 0, stream, emb, out0);
  }
}

// Round 7
// 168.829 us; speedup vs baseline: 1.2417x; 1.2417x over previous
//
#include <hip/hip_runtime.h>
#include <hip/hip_bf16.h>
#include <stdint.h>

#define NB 256
#define LQ 128
#define LC 512
#define DIM 384

typedef __attribute__((ext_vector_type(8))) short short8;
typedef __attribute__((ext_vector_type(4))) float f4;
typedef __attribute__((ext_vector_type(2))) float f2;
typedef __attribute__((ext_vector_type(2))) unsigned int u32x2;

__device__ __forceinline__ unsigned int pk2bf(float a, float b) {
  union { float f; uint32_t u; } x, y; x.f = a; y.f = b;
  uint32_t lo = (x.u + 0x7fffu + ((x.u >> 16) & 1u)) >> 16;
  uint32_t hi = (y.u + 0x7fffu + ((y.u >> 16) & 1u)) >> 16;
  return lo | (hi << 16);
}

__device__ __forceinline__ void gload16(const void* g, void* l) {
  __builtin_amdgcn_global_load_lds(
      (const __attribute__((address_space(1))) void*)g,
      (__attribute__((address_space(3))) void*)l, 16, 0, 0);
}

__device__ __forceinline__ void barrier_pinned() {
  __builtin_amdgcn_sched_barrier(0);
  __builtin_amdgcn_s_barrier();
  __builtin_amdgcn_sched_barrier(0);
}

// ============================== K1: normalize + pool =========================
// Round-7 theory: the ~2.7 TB/s wall was per-wave load ILP (VGPR=32 -> ~2
// loads in flight). Batch 8 rows: issue 24 independent f2 loads FIRST, then
// 8 interleaved shfl-reduce chains. Lane owns dims {2l,2l+1}+{128+..}+{256+..}.
template <int N>
__device__ __forceinline__ void batch_rows(const float* __restrict__ src0,
                                           const int* __restrict__ mask0,
                                           unsigned short* __restrict__ dst0,
                                           int lane, f2 (&acc)[3], float& cnt) {
  f2 v[N][3];
#pragma unroll
  for (int i = 0; i < N; ++i) {
    const f2* p = (const f2*)(src0 + (size_t)i * DIM);
#pragma unroll
    for (int j = 0; j < 3; ++j) v[i][j] = p[lane + 64 * j];
  }
  float ss[N];
#pragma unroll
  for (int i = 0; i < N; ++i)
    ss[i] = v[i][0].x * v[i][0].x + v[i][0].y * v[i][0].y
          + v[i][1].x * v[i][1].x + v[i][1].y * v[i][1].y
          + v[i][2].x * v[i][2].x + v[i][2].y * v[i][2].y;
#pragma unroll
  for (int o = 32; o; o >>= 1) {
#pragma unroll
    for (int i = 0; i < N; ++i) ss[i] += __shfl_xor(ss[i], o);
  }
#pragma unroll
  for (int i = 0; i < N; ++i) {
    const float inv = 1.0f / fmaxf(sqrtf(ss[i]), 1e-12f);
    const float fm = (float)mask0[i];
    cnt += fm;
#pragma unroll
    for (int j = 0; j < 3; ++j) acc[j] += v[i][j] * fm;
    unsigned int* drow = (unsigned int*)(dst0 + (size_t)i * DIM);
#pragma unroll
    for (int j = 0; j < 3; ++j)
      drow[lane + 64 * j] = pk2bf(v[i][j].x * inv, v[i][j].y * inv);
  }
}

__global__ __launch_bounds__(256, 4)
void normalize_pool(const float* __restrict__ qtok, const float* __restrict__ ctok,
                    const int* __restrict__ qm, const int* __restrict__ cm,
                    unsigned short* __restrict__ qn, unsigned short* __restrict__ cn,
                    float* __restrict__ pp, float* __restrict__ nn) {
  __shared__ float s_red[4][2][DIM];
  __shared__ float s_cnt[4][2];
  const int bid = blockIdx.x;
  const int b = bid >> 3, s = bid & 7;
  const int tid = threadIdx.x, wave = tid >> 6, lane = tid & 63;

  f2 accq[3] = {{0.f,0.f},{0.f,0.f},{0.f,0.f}};
  f2 accc[3] = {{0.f,0.f},{0.f,0.f},{0.f,0.f}};
  float cq = 0.f, cc = 0.f;

  {  // 4 q rows
    const int r0 = b * LQ + s * 16 + wave * 4;
    batch_rows<4>(qtok + (size_t)r0 * DIM, qm + r0, qn + (size_t)r0 * DIM,
                  lane, accq, cq);
  }
  {  // 16 c rows in two batches of 8
    const int r0 = b * LC + s * 64 + wave * 16;
    batch_rows<8>(ctok + (size_t)r0 * DIM, cm + r0, cn + (size_t)r0 * DIM,
                  lane, accc, cc);
    batch_rows<8>(ctok + (size_t)(r0 + 8) * DIM, cm + r0 + 8,
                  cn + (size_t)(r0 + 8) * DIM, lane, accc, cc);
  }

#pragma unroll
  for (int j = 0; j < 3; ++j) {
    *(f2*)&s_red[wave][0][128 * j + 2 * lane] = accq[j];
    *(f2*)&s_red[wave][1][128 * j + 2 * lane] = accc[j];
  }
  if (lane == 0) { s_cnt[wave][0] = cq; s_cnt[wave][1] = cc; }
  __syncthreads();

  for (int d = tid; d < DIM; d += 256) {
    float sq = 0.f, sc = 0.f;
#pragma unroll
    for (int w = 0; w < 4; ++w) { sq += s_red[w][0][d]; sc += s_red[w][1][d]; }
    pp[(size_t)bid * 768 + d] = sq;
    pp[(size_t)bid * 768 + DIM + d] = sc;
  }
  if (tid == 0) {
    nn[bid * 2]     = s_cnt[0][0] + s_cnt[1][0] + s_cnt[2][0] + s_cnt[3][0];
    nn[bid * 2 + 1] = s_cnt[0][1] + s_cnt[1][1] + s_cnt[2][1] + s_cnt[3][1];
  }
}

// ============================== K2: maxsim (MFMA) ============================
// grid 512: (b = bid>>1, c-half s = bid&1). 8 waves. q A-frags in registers;
// c staged via global_load_lds into a 3-buffer ring (32 rows x 768B, swizzled),
// counted vmcnt(3), one barrier per stage. Output: per-half row-max [128].
__global__ __launch_bounds__(512, 4)
void maxsim(const unsigned short* __restrict__ qn, const unsigned short* __restrict__ cn,
            const int* __restrict__ cm, float* __restrict__ ws_rm) {
  __shared__ __attribute__((aligned(128))) char ring[3][24576];
  __shared__ int s_cm[256];
  const int bid = blockIdx.x;
  const int b = bid >> 1, s = bid & 1;
  const int tid = threadIdx.x, wave = tid >> 6, lane = tid & 63;
  const int rA = lane & 15, hi = lane >> 4;

  if (tid < 256) s_cm[tid] = cm[b * LC + s * 256 + tid];
  __syncthreads();

  const char* qbase = (const char*)(qn + (size_t)b * LQ * DIM);
  const char* cbase = (const char*)(cn + (size_t)b * LC * DIM) + (size_t)s * 256 * 768;

  // per-lane swizzled DMA source offsets for one 32x768B tile (3 issues/lane):
  // LDS chunk n=(row,col) holds global chunk (row, col^(row&7)).
  int goff[3];
#pragma unroll
  for (int j = 0; j < 3; ++j) {
    const unsigned n = (unsigned)j * 512u + (unsigned)wave * 64u + (unsigned)lane;
    const unsigned row = n / 48u, col = n % 48u;
    goff[j] = (int)(row * 768u + ((col ^ (row & 7u)) << 4));
  }

  // ---- q prologue round A: tiles 0..2 -> bufs 0..2
#pragma unroll
  for (int tile = 0; tile < 3; ++tile) {
    char* dst = ring[tile] + wave * 1024;
#pragma unroll
    for (int j = 0; j < 3; ++j) gload16(qbase + tile * 24576 + goff[j], dst + j * 8192);
  }
  asm volatile("s_waitcnt vmcnt(0)" ::: "memory");
  barrier_pinned();

  short8 A[12] = {};
  if (wave < 6) {
    const char* bp = ring[wave >> 1];
    const int lr = (wave & 1) * 16 + rA;
#pragma unroll
    for (int kk = 0; kk < 12; ++kk)
      A[kk] = *(const short8*)(bp + lr * 768 + (((kk * 4 + hi) ^ (lr & 7)) << 4));
    asm volatile("s_waitcnt lgkmcnt(0)" ::: "memory");
  }
  barrier_pinned();

  // ---- round B: tile 3 -> buf 0 (waves 6,7 read their frags)
  {
    char* dst = ring[0] + wave * 1024;
#pragma unroll
    for (int j = 0; j < 3; ++j) gload16(qbase + 3 * 24576 + goff[j], dst + j * 8192);
  }
  asm volatile("s_waitcnt vmcnt(0)" ::: "memory");
  barrier_pinned();
  if (wave >= 6) {
    const char* bp = ring[0];
    const int lr = (wave - 6) * 16 + rA;
#pragma unroll
    for (int kk = 0; kk < 12; ++kk)
      A[kk] = *(const short8*)(bp + lr * 768 + (((kk * 4 + hi) ^ (lr & 7)) << 4));
    asm volatile("s_waitcnt lgkmcnt(0)" ::: "memory");
  }
  barrier_pinned();

  // ---- issue c0 -> buf1, c1 -> buf2
#pragma unroll
  for (int t0 = 0; t0 < 2; ++t0) {
    char* dst = ring[t0 + 1] + wave * 1024;
#pragma unroll
    for (int j = 0; j < 3; ++j) gload16(cbase + (size_t)t0 * 24576 + goff[j], dst + j * 8192);
  }

  float rm[4] = {-1e9f, -1e9f, -1e9f, -1e9f};

  // ---- 8 c stages; stage t reads buf[(t+1)%3], issues c(t+2) -> buf[(t+3)%3]
#pragma unroll
  for (int t = 0; t < 8; ++t) {
    if (t == 7) { asm volatile("s_waitcnt vmcnt(0)" ::: "memory"); }
    else        { asm volatile("s_waitcnt vmcnt(3)" ::: "memory"); }
    barrier_pinned();

    const char* bp = ring[(t + 1) % 3];
    f4 acc0 = {0,0,0,0}, acc1 = {0,0,0,0};
#pragma unroll
    for (int kk = 0; kk < 12; ++kk) {
      const int sw = ((kk * 4 + hi) ^ (rA & 7)) << 4;
      const short8 b0 = *(const short8*)(bp + rA * 768 + sw);
      const short8 b1 = *(const short8*)(bp + (rA + 16) * 768 + sw);
      acc0 = __builtin_amdgcn_mfma_f32_16x16x32_bf16(A[kk], b0, acc0, 0, 0, 0);
      acc1 = __builtin_amdgcn_mfma_f32_16x16x32_bf16(A[kk], b1, acc1, 0, 0, 0);
    }
    if (t + 2 < 8) {
      char* dst = ring[(t + 3) % 3] + wave * 1024;
#pragma unroll
      for (int j = 0; j < 3; ++j) gload16(cbase + (size_t)(t + 2) * 24576 + goff[j], dst + j * 8192);
    }
    const bool v0 = s_cm[t * 32 + rA] != 0;
    const bool v1 = s_cm[t * 32 + rA + 16] != 0;
#pragma unroll
    for (int r = 0; r < 4; ++r) {
      const float a0 = v0 ? acc0[r] : -1e9f;
      const float a1 = v1 ? acc1[r] : -1e9f;
      rm[r] = fmaxf(rm[r], fmaxf(a0, a1));
    }
  }

  // ---- reduce row-max across the 16 col-lanes; write per-half row-max
#pragma unroll
  for (int r = 0; r < 4; ++r) {
#pragma unroll
    for (int o = 1; o < 16; o <<= 1) rm[r] = fmaxf(rm[r], __shfl_xor(rm[r], o));
  }
  if (rA == 0) {
#pragma unroll
    for (int r = 0; r < 4; ++r)
      ws_rm[(size_t)bid * LQ + wave * 16 + hi * 4 + r] = rm[r];
  }
}

// ============================== K3: merge + MLP ==============================
__global__ __launch_bounds__(DIM)
void merge_mlp(const float* __restrict__ ws_rm, const float* __restrict__ pp,
               const float* __restrict__ nn, const int* __restrict__ qm,
               const float* __restrict__ W1, const float* __restrict__ b1,
               const float* __restrict__ W2, const float* __restrict__ b2,
               float* __restrict__ late, float* __restrict__ emb) {
  __shared__ float s_q[DIM], s_c[DIM], s_hq[DIM], s_hc[DIM];
  __shared__ float s_red[2][6], s_l[2];
  const int b = blockIdx.x;
  const int d = threadIdx.x;

  if (d < LQ) {
    const float m = fmaxf(ws_rm[(size_t)(2 * b) * LQ + d],
                          ws_rm[(size_t)(2 * b + 1) * LQ + d]);
    float ps = qm[b * LQ + d] ? m : 0.f;
#pragma unroll
    for (int o = 32; o; o >>= 1) ps += __shfl_xor(ps, o);
    if ((d & 63) == 0) s_l[d >> 6] = ps;
  }
  float sq = 0.f, sc = 0.f, nq = 0.f, nc = 0.f;
#pragma unroll
  for (int s = 0; s < 8; ++s) {
    sq += pp[(size_t)(b * 8 + s) * 768 + d];
    sc += pp[(size_t)(b * 8 + s) * 768 + DIM + d];
    nq += nn[(b * 8 + s) * 2];
    nc += nn[(b * 8 + s) * 2 + 1];
  }
  s_q[d] = sq / fmaxf(nq, 1e-9f);
  s_c[d] = sc / fmaxf(nc, 1e-9f);
  __syncthreads();

  float aq = b1[d], ac = b1[d];
#pragma unroll 8
  for (int k = 0; k < DIM; ++k) {
    const float w = W1[k * DIM + d];
    aq = fmaf(s_q[k], w, aq);
    ac = fmaf(s_c[k], w, ac);
  }
  s_hq[d] = fmaxf(aq, 0.f);
  s_hc[d] = fmaxf(ac, 0.f);
  __syncthreads();
  float pq = b2[d], pc = b2[d];
#pragma unroll 8
  for (int k = 0; k < DIM; ++k) {
    const float w = W2[k * DIM + d];
    pq = fmaf(s_hq[k], w, pq);
    pc = fmaf(s_hc[k], w, pc);
  }
  float q2 = pq * pq, c2 = pc * pc;
#pragma unroll
  for (int o = 32; o; o >>= 1) { q2 += __shfl_xor(q2, o); c2 += __shfl_xor(c2, o); }
  if ((d & 63) == 0) { s_red[0][d >> 6] = q2; s_red[1][d >> 6] = c2; }
  __syncthreads();
  float tq = 0.f, tc = 0.f;
#pragma unroll
  for (int w = 0; w < 6; ++w) { tq += s_red[0][w]; tc += s_red[1][w]; }
  emb[(size_t)b * DIM + d] = pq * (1.0f / fmaxf(sqrtf(tq), 1e-12f));
  emb[(size_t)(NB + b) * DIM + d] = pc * (1.0f / fmaxf(sqrtf(tc), 1e-12f));
  if (d == 0) late[b] = s_l[0] + s_l[1];
}

// ============================== K4: contrast =================================
__global__ __launch_bounds__(NB)
void contrast_kernel(const float* __restrict__ emb, float* __restrict__ out0) {
  __shared__ float s_q[DIM];
  const int i = blockIdx.x;
  for (int k = threadIdx.x; k < DIM; k += NB) s_q[k] = emb[(size_t)i * DIM + k];
  __syncthreads();
  const float* ce = emb + (size_t)(NB + threadIdx.x) * DIM;
  float acc = 0.f;
#pragma unroll 8
  for (int k = 0; k < DIM; ++k) acc = fmaf(s_q[k], ce[k], acc);
  out0[(size_t)i * NB + threadIdx.x] = acc / 0.07f;
}

// ===================== Fallback (round-1 proven path) ========================
#define TCD 32
#define QP 392
__device__ __forceinline__ unsigned short f2bf(float x) {
  union { float f; uint32_t u; } c; c.f = x;
  return (unsigned short)((c.u + 0x7fffu + ((c.u >> 16) & 1u)) >> 16);
}

__global__ __launch_bounds__(512, 1)
void fused_v1(const float* __restrict__ qtok, const float* __restrict__ ctok,
              const int* __restrict__ qm, const int* __restrict__ cm,
              float* __restrict__ pooled, float* __restrict__ late) {
  __shared__ unsigned short s_q[LQ][QP];
  __shared__ unsigned short s_c[TCD][QP];
  __shared__ float s_pq[8][DIM];
  __shared__ float s_pc[8][DIM];
  __shared__ float s_cnt[2][8];
  __shared__ int   s_cval[TCD];
  __shared__ float s_wsum[8];

  const int b = blockIdx.x;
  const int tid = threadIdx.x;
  const int wave = tid >> 6;
  const int lane = tid & 63;
  const int rA = lane & 15;
  const int kof = (lane >> 4) * 8;

  const float* qb = qtok + (size_t)b * LQ * DIM;
  const float* cb = ctok + (size_t)b * LC * DIM;
  const int* qmb = qm + b * LQ;
  const int* cmb = cm + b * LC;

  float pq[6] = {0.f,0.f,0.f,0.f,0.f,0.f};
  float cq = 0.f;
  for (int r0 = 0; r0 < 16; ++r0) {
    const int r = wave * 16 + r0;
    const float* src = qb + r * DIM;
    float v[6], ss = 0.f;
#pragma unroll
    for (int j = 0; j < 6; ++j) { v[j] = src[lane + 64 * j]; ss += v[j] * v[j]; }
#pragma unroll
    for (int o = 32; o; o >>= 1) ss += __shfl_xor(ss, o);
    const float inv = 1.0f / fmaxf(sqrtf(ss), 1e-12f);
    const float fm = (float)qmb[r];
#pragma unroll
    for (int j = 0; j < 6; ++j) {
      s_q[r][lane + 64 * j] = f2bf(v[j] * inv);
      pq[j] = fmaf(v[j], fm, pq[j]);
    }
    cq += fm;
  }
#pragma unroll
  for (int j = 0; j < 6; ++j) s_pq[wave][lane + 64 * j] = pq[j];
  if (lane == 0) s_cnt[0][wave] = cq;

  float rm[4] = {-1e9f, -1e9f, -1e9f, -1e9f};
  float pc[6] = {0.f,0.f,0.f,0.f,0.f,0.f};
  float cc = 0.f;

  for (int t = 0; t < LC / TCD; ++t) {
    __syncthreads();
#pragma unroll
    for (int r0 = 0; r0 < 4; ++r0) {
      const int r = wave * 4 + r0;
      const int crow = t * TCD + r;
      const float* src = cb + crow * DIM;
      float v[6], ss = 0.f;
#pragma unroll
      for (int j = 0; j < 6; ++j) { v[j] = src[lane + 64 * j]; ss += v[j] * v[j]; }
#pragma unroll
      for (int o = 32; o; o >>= 1) ss += __shfl_xor(ss, o);
      const float inv = 1.0f / fmaxf(sqrtf(ss), 1e-12f);
      const int mk = cmb[crow];
      const float fm = (float)mk;
#pragma unroll
      for (int j = 0; j < 6; ++j) {
        s_c[r][lane + 64 * j] = f2bf(v[j] * inv);
        pc[j] = fmaf(v[j], fm, pc[j]);
      }
      cc += fm;
      if (lane == 0) s_cval[r] = mk;
    }
    __syncthreads();

    const unsigned short* ap  = &s_q[wave * 16 + rA][kof];
    const unsigned short* bp0 = &s_c[rA][kof];
    const unsigned short* bp1 = &s_c[rA + 16][kof];
    f4 acc0 = {0.f,0.f,0.f,0.f};
    f4 acc1 = {0.f,0.f,0.f,0.f};
#pragma unroll
    for (int kk = 0; kk < 12; ++kk) {
      short8 a  = *(const short8*)(ap  + kk * 32);
      short8 b0 = *(const short8*)(bp0 + kk * 32);
      short8 b1 = *(const short8*)(bp1 + kk * 32);
      acc0 = __builtin_amdgcn_mfma_f32_16x16x32_bf16(a, b0, acc0, 0, 0, 0);
      acc1 = __builtin_amdgcn_mfma_f32_16x16x32_bf16(a, b1, acc1, 0, 0, 0);
    }
    const bool v0 = s_cval[rA] != 0;
    const bool v1 = s_cval[rA + 16] != 0;
#pragma unroll
    for (int r = 0; r < 4; ++r) {
      const float a0 = v0 ? acc0[r] : -1e9f;
      const float a1 = v1 ? acc1[r] : -1e9f;
      rm[r] = fmaxf(rm[r], fmaxf(a0, a1));
    }
  }

#pragma unroll
  for (int j = 0; j < 6; ++j) s_pc[wave][tid & 63 ? lane + 64 * j : lane + 64 * j] = pc[j];
  if (lane == 0) s_cnt[1][wave] = cc;

#pragma unroll
  for (int r = 0; r < 4; ++r) {
#pragma unroll
    for (int o = 1; o < 16; o <<= 1) rm[r] = fmaxf(rm[r], __shfl_xor(rm[r], o));
  }
  float ps = 0.f;
  if (rA == 0) {
    const int rowb = wave * 16 + (lane >> 4) * 4;
#pragma unroll
    for (int r = 0; r < 4; ++r) ps += qmb[rowb + r] ? rm[r] : 0.f;
  }
#pragma unroll
  for (int o = 32; o; o >>= 1) ps += __shfl_xor(ps, o);
  if (lane == 0) s_wsum[wave] = ps;
  __syncthreads();

  if (tid < DIM) {
    float sq = 0.f, sc = 0.f, nq = 0.f, nc = 0.f;
#pragma unroll
    for (int w = 0; w < 8; ++w) {
      sq += s_pq[w][tid];
      sc += s_pc[w][tid];
      nq += s_cnt[0][w];
      nc += s_cnt[1][w];
    }
    pooled[b * DIM + tid] = sq / fmaxf(nq, 1e-9f);
    pooled[(NB + b) * DIM + tid] = sc / fmaxf(nc, 1e-9f);
  }
  if (tid == 0) {
    float tot = 0.f;
#pragma unroll
    for (int w = 0; w < 8; ++w) tot += s_wsum[w];
    late[b] = tot;
  }
}

__global__ __launch_bounds__(DIM)
void mlp_v1(const float* __restrict__ pooled,
            const float* __restrict__ W1, const float* __restrict__ b1,
            const float* __restrict__ W2, const float* __restrict__ b2,
            float* __restrict__ emb) {
  __shared__ float s_in[DIM];
  __shared__ float s_h[DIM];
  __shared__ float s_red[6];
  const int row = blockIdx.y * NB + blockIdx.x;
  const int d = threadIdx.x;
  s_in[d] = pooled[(size_t)row * DIM + d];
  __syncthreads();
  float acc = b1[d];
#pragma unroll 8
  for (int k = 0; k < DIM; ++k) acc = fmaf(s_in[k], W1[k * DIM + d], acc);
  s_h[d] = fmaxf(acc, 0.f);
  __syncthreads();
  float p = b2[d];
#pragma unroll 8
  for (int k = 0; k < DIM; ++k) p = fmaf(s_h[k], W2[k * DIM + d], p);
  float ss = p * p;
#pragma unroll
  for (int o = 32; o; o >>= 1) ss += __shfl_xor(ss, o);
  if ((d & 63) == 0) s_red[d >> 6] = ss;
  __syncthreads();
  float tot = 0.f;
#pragma unroll
  for (int w = 0; w < 6; ++w) tot += s_red[w];
  emb[(size_t)row * DIM + d] = p * (1.0f / fmaxf(sqrtf(tot), 1e-12f));
}

// ============================== launch =======================================
extern "C" void kernel_launch(void* const* d_in, const int* in_sizes, int n_in,
                              void* d_out, int out_size, void* d_ws, size_t ws_size,
                              hipStream_t stream) {
  const float* qtok = (const float*)d_in[0];
  const float* ctok = (const float*)d_in[1];
  const int*   qmm  = (const int*)d_in[2];
  const int*   cmm  = (const int*)d_in[3];
  const float* W1   = (const float*)d_in[4];
  const float* b1   = (const float*)d_in[5];
  const float* W2   = (const float*)d_in[6];
  const float* b2   = (const float*)d_in[7];

  float* out0 = (float*)d_out;   // [NB*NB]
  float* late = out0 + NB * NB;  // [NB]

  // main-path workspace layout
  const size_t PP_N   = (size_t)2048 * 768;
  const size_t NN_N   = 4096;
  const size_t RM_N   = (size_t)512 * LQ;
  const size_t EMB_N  = (size_t)2 * NB * DIM;
  const size_t QN_N   = (size_t)NB * LQ * DIM;
  const size_t CN_N   = (size_t)NB * LC * DIM;
  const size_t NEED   = (PP_N + NN_N + RM_N + EMB_N) * 4 + (QN_N + CN_N) * 2;

  if (ws_size >= NEED) {
    float* pp  = (float*)d_ws;
    float* nn  = pp + PP_N;
    float* rm  = nn + NN_N;
    float* emb = rm + RM_N;
    unsigned short* qn = (unsigned short*)(emb + EMB_N);
    unsigned short* cn = qn + QN_N;

    hipLaunchKernelGGL(normalize_pool, dim3(2048), dim3(256), 0, stream,
                       qtok, ctok, qmm, cmm, qn, cn, pp, nn);
    hipLaunchKernelGGL(maxsim, dim3(512), dim3(512), 0, stream, qn, cn, cmm, rm);
    hipLaunchKernelGGL(merge_mlp, dim3(NB), dim3(DIM), 0, stream,
                       rm, pp, nn, qmm, W1, b1, W2, b2, late, emb);
    hipLaunchKernelGGL(contrast_kernel, dim3(NB), dim3(NB), 0, stream, emb, out0);
  } else {
    float* pooled = (float*)d_ws;            // [2*NB][DIM]
    float* emb    = pooled + 2 * NB * DIM;   // [2*NB][DIM]
    hipLaunchKernelGGL(fused_v1, dim3(NB), dim3(512), 0, stream,
                       qtok, ctok, qmm, cmm, pooled, late);
    hipLaunchKernelGGL(mlp_v1, dim3(NB, 2), dim3(DIM), 0, stream,
                       pooled, W1, b1, W2, b2, emb);
    hipLaunchKernelGGL(contrast_kernel, dim3(NB), dim3(NB), 0, stream, emb, out0);
  }
}